// Round 5
// baseline (448.000 us; speedup 1.0000x reference)
//
#include <hip/hip_runtime.h>

// GraphAttentionLayer v7: B=16, M=2048, F_IN=128, F_OUT=64, ALPHA=0.2
// out = elu( softmax_j( mask(adj, leaky_relu(f1_i + f2_j)) ) @ (h@W) )
// Algebra: h' = ((P @ h) @ W)/den, f1 = h@(W@a1), f2 = h@(W@a2).
//
// v7 = v6 with a REAL software pipeline. v5/v6 both landed ~160 us because
// their prefetch was self-draining:
//  - vmcnt is IN-ORDER: waiting on the last-issued load waits on everything
//    older. v6 issued the t+3 adj (HBM) before the t hbf frags, so the MFMA's
//    wait was vmcnt(0) -> every iter ate full HBM latency.
//  - v5's register rotations (bC=bN, aA0=aB0) are v_movs reading just-issued
//    load dests -> compiler-inserted waitcnt -> same drain.
// Fix: static renaming. Token loop = 16 outer x 4 unrolled stages:
//  - adj in aP0/aP1[4], consumed exactly 4 stages after issue (>1200 cy).
//  - B-frags ping-pong bbA/bbB, consumed 1 stage after issue (~300 cy L2).
//  - stage order: {bb-next, f2 LDS, scores(old adj), adj-reload, MFMA(old bb)}
//    -> all waits are counted vmcnt(>=10); the HBM stream never drains.
// All buffer indices compile-time constant (no scratch). VGPR ~155 ->
// __launch_bounds__(128,3). k_prep / numerics / epilogue unchanged.

#define M_     2048
#define FIN_   128
#define F_     64
#define ALPHA_ 0.2f
#define HS_    132     // k_prep LDS h-tile stride (floats)
#define WT_    132     // Tsum row stride (floats)

typedef float  float4_ __attribute__((ext_vector_type(4)));
typedef short  short8  __attribute__((ext_vector_type(8)));
typedef int    int4_   __attribute__((ext_vector_type(4)));
typedef unsigned int u32x4 __attribute__((ext_vector_type(4)));
typedef unsigned short u16;
typedef unsigned int   u32;

// packed f32x2 -> bf16x2 (RNE)
static __device__ __forceinline__ u32 cvtpk(float lo, float hi) {
    u32 r;
    asm("v_cvt_pk_bf16_f32 %0, %1, %2" : "=v"(r) : "v"(lo), "v"(hi));
    return r;
}

// ---------------------------------------------------------------------------
// Phase 1: hbf fragment layout: ((b*64 + t)*8 + nt)*64 + l  (16B per entry)
//   lane l of a wave holds B[n = nt*16 + (l&15)][k = (l>>4)*8 .. +7]
//   (tokens packed pairwise: u32 = bf16(tok_even) | bf16(tok_odd)<<16)
// ---------------------------------------------------------------------------
__global__ __launch_bounds__(256, 4) void k_prep(
    const float* __restrict__ h, const float* __restrict__ W,
    const float* __restrict__ a, u16* __restrict__ hbf,
    float* __restrict__ f1all, float* __restrict__ f2all)
{
    __shared__ float a_s[2 * F_];
    __shared__ float wa1[FIN_], wa2[FIN_];
    __shared__ float hs[32 * HS_];

    const int tid = threadIdx.x;
    const u32 bid = blockIdx.x;
    const u32 lg  = (bid & 7) * 128 + (bid >> 3);   // XCD x produces batches 2x,2x+1
    const int b   = lg >> 6;
    const int t   = lg & 63;

    if (tid < 128) a_s[tid] = a[tid];

    // h tile -> regs (coalesced float4)
    const int tok = tid >> 3, f0 = (tid & 7) * 16;
    const float* hp = h + ((size_t)(b * M_ + t * 32 + tok)) * FIN_ + f0;
    float4_ x0 = *(const float4_*)hp;
    float4_ x1 = *(const float4_*)(hp + 4);
    float4_ x2 = *(const float4_*)(hp + 8);
    float4_ x3 = *(const float4_*)(hp + 12);
    __syncthreads();   // a_s ready

    if (tid < FIN_) {
        float s1 = 0.f, s2 = 0.f;
#pragma unroll 8
        for (int n = 0; n < F_; ++n) {
            float wv = W[tid * F_ + n];
            s1 += wv * a_s[n];
            s2 += wv * a_s[F_ + n];
        }
        wa1[tid] = s1;
        wa2[tid] = s2;
    }

    float* hr = hs + tok * HS_ + f0;
    *(float4_*)(hr)      = x0;
    *(float4_*)(hr + 4)  = x1;
    *(float4_*)(hr + 8)  = x2;
    *(float4_*)(hr + 12) = x3;
    __syncthreads();   // hs + wa ready

    // ---- fragment conversion: thread handles lane l for nt0, nt0+1 ----
    {
        const int l = tid & 63, lc = l & 15, q = l >> 4;
        const int nt0 = (tid >> 6) * 2;
        u32x4* ob = (u32x4*)hbf + ((size_t)(b * 64 + t)) * 8 * 64;
#pragma unroll
        for (int ni = 0; ni < 2; ++ni) {
            const int nt = nt0 + ni;
            const float* cp = hs + (q * 8) * HS_ + nt * 16 + lc;
            u32x4 wv;
            wv[0] = cvtpk(cp[0 * HS_], cp[1 * HS_]);
            wv[1] = cvtpk(cp[2 * HS_], cp[3 * HS_]);
            wv[2] = cvtpk(cp[4 * HS_], cp[5 * HS_]);
            wv[3] = cvtpk(cp[6 * HS_], cp[7 * HS_]);
            ob[nt * 64 + l] = wv;
        }
    }

    // ---- f1/f2 per token (same reduction order as v6) ----
    {
        const int r = tid >> 3, k0 = (tid & 7) * 16;
        const float* rp = hs + r * HS_ + k0;
        float s1 = 0.f, s2 = 0.f;
#pragma unroll
        for (int k = 0; k < 16; ++k) {
            s1 += rp[k] * wa1[k0 + k];
            s2 += rp[k] * wa2[k0 + k];
        }
        s1 += __shfl_xor(s1, 1, 64); s2 += __shfl_xor(s2, 1, 64);
        s1 += __shfl_xor(s1, 2, 64); s2 += __shfl_xor(s2, 2, 64);
        s1 += __shfl_xor(s1, 4, 64); s2 += __shfl_xor(s2, 4, 64);
        if ((tid & 7) == 0) {
            f1all[b * M_ + t * 32 + r] = s1;
            f2all[b * M_ + t * 32 + r] = s2;
        }
    }
}

// ---------------------------------------------------------------------------
// Phase 2: 1024 blocks x 128 thr (2 waves). Wave = 16 rows x 128 feats.
// Zero barriers in the token loop; statically-renamed prefetch pipeline.
// ---------------------------------------------------------------------------
__global__ __launch_bounds__(128, 3) void k_main(
    const int* __restrict__ adj, const u16* __restrict__ hbf,
    const float* __restrict__ f1all, const float* __restrict__ f2all,
    const float* __restrict__ W, float* __restrict__ out)
{
    __shared__ char  dyn[WT_ * 32 * 4];   // f2s (8 KB) then Tsum (16.9 KB)
    __shared__ float dens[32];

    float* f2s  = (float*)dyn;
    float* Tsum = (float*)dyn;

    const int tid  = threadIdx.x;
    const int w    = tid >> 6;
    const int l    = tid & 63;
    const int lc   = l & 15;
    const int quad = l >> 4;

    const u32 bid = blockIdx.x;
    const u32 lg  = (bid & 7) * 128 + (bid >> 3);   // XCD x consumes batches 2x,2x+1
    const int b   = lg >> 6;
    const int i0  = (lg & 63) * 32;
    const int rowbase = i0 + w * 16;

    // stage f2all[b] -> LDS (8 KB, broadcast-read in loop)
    {
        const int o = tid * 16;
        float4_ v0 = *(const float4_*)(f2all + b * M_ + o);
        float4_ v1 = *(const float4_*)(f2all + b * M_ + o + 4);
        float4_ v2 = *(const float4_*)(f2all + b * M_ + o + 8);
        float4_ v3 = *(const float4_*)(f2all + b * M_ + o + 12);
        *(float4_*)(f2s + o)      = v0;
        *(float4_*)(f2s + o + 4)  = v1;
        *(float4_*)(f2s + o + 8)  = v2;
        *(float4_*)(f2s + o + 12) = v3;
    }

    const float f1r = f1all[b * M_ + rowbase + lc];
    const int* aprow = adj + ((size_t)(b * M_ + rowbase + lc)) * M_ + quad * 8;
    const u32x4* hb  = (const u32x4*)hbf + ((size_t)b * 64) * 8 * 64 + l;

    // prologue: adj tiles 0..3 into the 4 static slots; B-frags tile 0 -> bbA
    int4_ aP0[4], aP1[4];
#pragma unroll
    for (int i = 0; i < 4; ++i) {
        aP0[i] = *(const int4_*)(aprow + i * 32);
        aP1[i] = *(const int4_*)(aprow + i * 32 + 4);
    }
    u32x4 bbA[8], bbB[8];
#pragma unroll
    for (int nt = 0; nt < 8; ++nt) bbA[nt] = hb[nt * 64];

    __syncthreads();   // f2s ready

    float denacc = 0.f;
    float4_ acc[8];
#pragma unroll
    for (int nt = 0; nt < 8; ++nt) acc[nt] = (float4_){0.f, 0.f, 0.f, 0.f};

#define SC(GE, GO, AE, AO, IDX)                                 \
        {                                                       \
            float xe = f1r + (GE); xe = fmaxf(xe, ALPHA_ * xe); \
            float xo = f1r + (GO); xo = fmaxf(xo, ALPHA_ * xo); \
            float ee = ((AE) > 0) ? __expf(xe) : 0.f;           \
            float eo = ((AO) > 0) ? __expf(xo) : 0.f;           \
            u32 pk = cvtpk(ee, eo);                             \
            d += __uint_as_float(pk << 16);                     \
            d += __uint_as_float(pk & 0xFFFF0000u);             \
            pw[IDX] = pk;                                       \
        }

// One pipeline stage for tile T (stage index I in 0..3):
//  (a) issue next tile's B-frags into BN        [consumed next stage]
//  (b) read f2 pair from LDS
//  (c) scores consume aP[I] (issued 4 stages ago -> counted vmcnt, no drain)
//  (d) reload aP[I] with tile T+4 (HBM stream)
//  (e) MFMA consumes BC (issued last stage -> vmcnt(12), adj stays in flight)
#define STAGE(T, I, BC, BN)                                                   \
    {                                                                         \
        const int tn = ((T) < 63) ? (T) + 1 : 63;                             \
        const int tp = ((T) < 60) ? (T) + 4 : 63;                             \
        _Pragma("unroll")                                                     \
        for (int nt = 0; nt < 8; ++nt) BN[nt] = hb[(tn * 8 + nt) * 64];       \
        float4_ g0 = *(const float4_*)(f2s + (T) * 32 + quad * 8);            \
        float4_ g1 = *(const float4_*)(f2s + (T) * 32 + quad * 8 + 4);        \
        u32x4 pw;                                                             \
        float d = 0.f;                                                        \
        SC(g0[0], g0[1], aP0[I][0], aP0[I][1], 0)                             \
        SC(g0[2], g0[3], aP0[I][2], aP0[I][3], 1)                             \
        SC(g1[0], g1[1], aP1[I][0], aP1[I][1], 2)                             \
        SC(g1[2], g1[3], aP1[I][2], aP1[I][3], 3)                             \
        denacc += d;                                                          \
        const short8 af = __builtin_bit_cast(short8, pw);                     \
        aP0[I] = *(const int4_*)(aprow + tp * 32);                            \
        aP1[I] = *(const int4_*)(aprow + tp * 32 + 4);                        \
        _Pragma("unroll")                                                     \
        for (int nt = 0; nt < 8; ++nt)                                        \
            acc[nt] = __builtin_amdgcn_mfma_f32_16x16x32_bf16(                \
                af, __builtin_bit_cast(short8, BC[nt]), acc[nt], 0, 0, 0);    \
    }

    for (int o = 0; o < 16; ++o) {
        const int t0 = o * 4;
        STAGE(t0 + 0, 0, bbA, bbB)
        STAGE(t0 + 1, 1, bbB, bbA)
        STAGE(t0 + 2, 2, bbA, bbB)
        STAGE(t0 + 3, 3, bbB, bbA)
    }
#undef STAGE
#undef SC

    // ---- denom: reduce over the 4 quads ----
    denacc += __shfl_xor(denacc, 16, 64);
    denacc += __shfl_xor(denacc, 32, 64);
    if (quad == 0) dens[w * 16 + lc] = denacc;
    __syncthreads();   // f2s dead; Tsum alias safe

    // ---- T -> LDS (disjoint per wave) ----
#pragma unroll
    for (int nt = 0; nt < 8; ++nt)
#pragma unroll
        for (int mm = 0; mm < 4; ++mm)
            Tsum[(w * 16 + quad * 4 + mm) * WT_ + nt * 16 + lc] = acc[nt][mm];
    __syncthreads();

    // ---- epilogue: out = elu( (T @ W_fp32) / den ), 32 rows in 2 passes ----
#pragma unroll
    for (int rr = 0; rr < 2; ++rr) {
        const int r  = (tid >> 3) + rr * 16;
        const int n0 = (tid & 7) * 8;
        const float den  = dens[r];
        const float rden = (den > 0.f) ? (1.f / den) : 0.f;
        float u[8];
#pragma unroll
        for (int nn = 0; nn < 8; ++nn) u[nn] = 0.f;
#pragma unroll 4
        for (int k = 0; k < FIN_; ++k) {
            const float tv = Tsum[r * WT_ + k];
            float4_ wv0 = *(const float4_*)(W + k * F_ + n0);
            float4_ wv1 = *(const float4_*)(W + k * F_ + n0 + 4);
            u[0] += tv * wv0[0]; u[1] += tv * wv0[1];
            u[2] += tv * wv0[2]; u[3] += tv * wv0[3];
            u[4] += tv * wv1[0]; u[5] += tv * wv1[1];
            u[6] += tv * wv1[2]; u[7] += tv * wv1[3];
        }
        float4_ o0, o1;
#pragma unroll
        for (int nn = 0; nn < 8; ++nn) {
            float hp = u[nn] * rden;
            float o  = hp > 0.f ? hp : expm1f(hp);
            if (nn < 4) o0[nn] = o; else o1[nn - 4] = o;
        }
        float* op = out + ((size_t)(b * M_ + i0 + r)) * F_ + n0;
        *(float4_*)op       = o0;
        *(float4_*)(op + 4) = o1;
    }
}

// ---------------------------------------------------------------------------
extern "C" void kernel_launch(void* const* d_in, const int* in_sizes, int n_in,
                              void* d_out, int out_size, void* d_ws, size_t ws_size,
                              hipStream_t stream)
{
    (void)out_size; (void)ws_size;
    const float* h  = (const float*)d_in[0];
    const int* adjp = (const int*)d_in[1];
    const float* Wp = (const float*)d_in[2];
    const float* ap = (const float*)d_in[3];
    for (int i = 0; i < n_in; ++i) {
        long s = in_sizes[i];
        if      (s == 4194304L)  h    = (const float*)d_in[i];
        else if (s == 67108864L) adjp = (const int*)d_in[i];
        else if (s == 8192L)     Wp   = (const float*)d_in[i];
        else if (s == 128L)      ap   = (const float*)d_in[i];
    }
    u16*   hbf   = (u16*)d_ws;                                  // 8 MB
    float* f1all = (float*)((char*)d_ws + (8u << 20));          // 128 KB
    float* f2all = f1all + 16 * M_;                             // 128 KB
    k_prep<<<1024, 256, 0, stream>>>(h, Wp, ap, hbf, f1all, f2all);
    k_main<<<1024, 128, 0, stream>>>(adjp, hbf, f1all, f2all, Wp, (float*)d_out);
}

// Round 6
// 444.962 us; speedup vs baseline: 1.0068x; 1.0068x over previous
//
#include <hip/hip_runtime.h>

// GraphAttentionLayer v8: B=16, M=2048, F_IN=128, F_OUT=64, ALPHA=0.2
// out = elu( softmax_j( mask(adj, leaky_relu(f1_i + f2_j)) ) @ (h@W) )
// Algebra: h' = ((P @ h) @ W)/den, f1 = h@(W@a1), f2 = h@(W@a2).
//
// v8 theory: v5/v6/v7 all ~160-170 us because (a) the 256 MB adj stream
// thrashes L2 (32 MB/XCD through 4 MB) and L3, so the 1 GB of hbf B-frag
// re-reads miss to L3/HBM latency; (b) grid gave only 2 waves/SIMD to hide
// it. Fixes:
//  - adj loads NON-TEMPORAL (nt bit): one-shot stream stops evicting hbf
//    -> hbf[b] (1 MB/XCD) stays L2-resident, bb loads ~200cy hits.
//  - token-split x2: block = 4 waves = 2 row-groups x 2 token-halves,
//    32 tiles/wave -> 4096 waves = 16/CU = 4/SIMD (2x TLP), traffic-neutral.
//    Partials merged post-loop in LDS (3 barriers total, none in loop).
//  - adj depth-2 static ping-pong (consume-before-reload), bb loaded at
//    stage top -> counted vmcnt waits only.
// VGPR ~105 (<=128 cap of __launch_bounds__(256,4)). k_prep unchanged.

#define M_     2048
#define FIN_   128
#define F_     64
#define ALPHA_ 0.2f
#define HS_    132     // k_prep LDS h-tile stride (floats)
#define WT_    132     // Tsum row stride (floats)

typedef float  float4_ __attribute__((ext_vector_type(4)));
typedef short  short8  __attribute__((ext_vector_type(8)));
typedef int    int4_   __attribute__((ext_vector_type(4)));
typedef unsigned int u32x4 __attribute__((ext_vector_type(4)));
typedef unsigned short u16;
typedef unsigned int   u32;

// packed f32x2 -> bf16x2 (RNE)
static __device__ __forceinline__ u32 cvtpk(float lo, float hi) {
    u32 r;
    asm("v_cvt_pk_bf16_f32 %0, %1, %2" : "=v"(r) : "v"(lo), "v"(hi));
    return r;
}

// non-temporal 16B load (nt cache bit: don't retain in L2/L3)
static __device__ __forceinline__ int4_ ntload4(const int* p) {
    return __builtin_nontemporal_load((const int4_*)p);
}

// ---------------------------------------------------------------------------
// Phase 1: hbf fragment layout: ((b*64 + t)*8 + nt)*64 + l  (16B per entry)
//   lane l of a wave holds B[n = nt*16 + (l&15)][k = (l>>4)*8 .. +7]
//   (tokens packed pairwise: u32 = bf16(tok_even) | bf16(tok_odd)<<16)
// ---------------------------------------------------------------------------
__global__ __launch_bounds__(256, 4) void k_prep(
    const float* __restrict__ h, const float* __restrict__ W,
    const float* __restrict__ a, u16* __restrict__ hbf,
    float* __restrict__ f1all, float* __restrict__ f2all)
{
    __shared__ float a_s[2 * F_];
    __shared__ float wa1[FIN_], wa2[FIN_];
    __shared__ float hs[32 * HS_];

    const int tid = threadIdx.x;
    const u32 bid = blockIdx.x;
    const u32 lg  = (bid & 7) * 128 + (bid >> 3);   // XCD x produces batches 2x,2x+1
    const int b   = lg >> 6;
    const int t   = lg & 63;

    if (tid < 128) a_s[tid] = a[tid];

    // h tile -> regs (coalesced float4)
    const int tok = tid >> 3, f0 = (tid & 7) * 16;
    const float* hp = h + ((size_t)(b * M_ + t * 32 + tok)) * FIN_ + f0;
    float4_ x0 = *(const float4_*)hp;
    float4_ x1 = *(const float4_*)(hp + 4);
    float4_ x2 = *(const float4_*)(hp + 8);
    float4_ x3 = *(const float4_*)(hp + 12);
    __syncthreads();   // a_s ready

    if (tid < FIN_) {
        float s1 = 0.f, s2 = 0.f;
#pragma unroll 8
        for (int n = 0; n < F_; ++n) {
            float wv = W[tid * F_ + n];
            s1 += wv * a_s[n];
            s2 += wv * a_s[F_ + n];
        }
        wa1[tid] = s1;
        wa2[tid] = s2;
    }

    float* hr = hs + tok * HS_ + f0;
    *(float4_*)(hr)      = x0;
    *(float4_*)(hr + 4)  = x1;
    *(float4_*)(hr + 8)  = x2;
    *(float4_*)(hr + 12) = x3;
    __syncthreads();   // hs + wa ready

    // ---- fragment conversion: thread handles lane l for nt0, nt0+1 ----
    {
        const int l = tid & 63, lc = l & 15, q = l >> 4;
        const int nt0 = (tid >> 6) * 2;
        u32x4* ob = (u32x4*)hbf + ((size_t)(b * 64 + t)) * 8 * 64;
#pragma unroll
        for (int ni = 0; ni < 2; ++ni) {
            const int nt = nt0 + ni;
            const float* cp = hs + (q * 8) * HS_ + nt * 16 + lc;
            u32x4 wv;
            wv[0] = cvtpk(cp[0 * HS_], cp[1 * HS_]);
            wv[1] = cvtpk(cp[2 * HS_], cp[3 * HS_]);
            wv[2] = cvtpk(cp[4 * HS_], cp[5 * HS_]);
            wv[3] = cvtpk(cp[6 * HS_], cp[7 * HS_]);
            ob[nt * 64 + l] = wv;
        }
    }

    // ---- f1/f2 per token (same reduction order as v7) ----
    {
        const int r = tid >> 3, k0 = (tid & 7) * 16;
        const float* rp = hs + r * HS_ + k0;
        float s1 = 0.f, s2 = 0.f;
#pragma unroll
        for (int k = 0; k < 16; ++k) {
            s1 += rp[k] * wa1[k0 + k];
            s2 += rp[k] * wa2[k0 + k];
        }
        s1 += __shfl_xor(s1, 1, 64); s2 += __shfl_xor(s2, 1, 64);
        s1 += __shfl_xor(s1, 2, 64); s2 += __shfl_xor(s2, 2, 64);
        s1 += __shfl_xor(s1, 4, 64); s2 += __shfl_xor(s2, 4, 64);
        if ((tid & 7) == 0) {
            f1all[b * M_ + t * 32 + r] = s1;
            f2all[b * M_ + t * 32 + r] = s2;
        }
    }
}

// ---------------------------------------------------------------------------
// Phase 2: 1024 blocks x 256 thr (4 waves). Wave (wr, wh): rows wr*16..+15
// of the block's 32, token half wh (32 tiles). Zero barriers in loop;
// token-half partials merged in LDS afterwards.
// ---------------------------------------------------------------------------
__global__ __launch_bounds__(256, 4) void k_main(
    const int* __restrict__ adj, const u16* __restrict__ hbf,
    const float* __restrict__ f1all, const float* __restrict__ f2all,
    const float* __restrict__ W, float* __restrict__ out)
{
    __shared__ char  dyn[WT_ * 32 * 4];   // f2s (8 KB) then Tsum (16.9 KB)
    __shared__ float dens2[64];

    float* f2s  = (float*)dyn;
    float* Tsum = (float*)dyn;

    const int tid  = threadIdx.x;
    const int w    = tid >> 6;
    const int l    = tid & 63;
    const int lc   = l & 15;
    const int quad = l >> 4;
    const int wr   = w & 1;      // row group (16 rows)
    const int wh   = w >> 1;     // token half (32 tiles)

    const u32 bid = blockIdx.x;
    const u32 lg  = (bid & 7) * 128 + (bid >> 3);   // XCD x consumes batches 2x,2x+1
    const int b   = lg >> 6;
    const int i0  = (lg & 63) * 32;
    const int rowbase = i0 + wr * 16;

    // stage f2all[b] -> LDS (8 KB, broadcast-read in loop)
    {
        const int o = tid * 8;
        float4_ v0 = *(const float4_*)(f2all + b * M_ + o);
        float4_ v1 = *(const float4_*)(f2all + b * M_ + o + 4);
        *(float4_*)(f2s + o)     = v0;
        *(float4_*)(f2s + o + 4) = v1;
    }

    const float f1r = f1all[b * M_ + rowbase + lc];
    const int* aprow = adj + ((size_t)(b * M_ + rowbase + lc)) * M_ + quad * 8;
    const u32x4* hb  = (const u32x4*)hbf + ((size_t)b * 64) * 8 * 64 + l;

    const int t0 = wh * 32;            // wave's first tile
    const int tE = t0 + 31;            // wave's last tile (clamp target)

    // prologue: adj tiles t0, t0+1 (nt, depth 2)
    int4_ aA0 = ntload4(aprow + t0 * 32);
    int4_ aA1 = ntload4(aprow + t0 * 32 + 4);
    int4_ aB0 = ntload4(aprow + (t0 + 1) * 32);
    int4_ aB1 = ntload4(aprow + (t0 + 1) * 32 + 4);

    __syncthreads();   // f2s ready

    float denacc = 0.f;
    float4_ acc[8];
#pragma unroll
    for (int nt = 0; nt < 8; ++nt) acc[nt] = (float4_){0.f, 0.f, 0.f, 0.f};

#define SC(GE, GO, AE, AO, IDX)                                 \
        {                                                       \
            float xe = f1r + (GE); xe = fmaxf(xe, ALPHA_ * xe); \
            float xo = f1r + (GO); xo = fmaxf(xo, ALPHA_ * xo); \
            float ee = ((AE) > 0) ? __expf(xe) : 0.f;           \
            float eo = ((AO) > 0) ? __expf(xo) : 0.f;           \
            u32 pk = cvtpk(ee, eo);                             \
            d += __uint_as_float(pk << 16);                     \
            d += __uint_as_float(pk & 0xFFFF0000u);             \
            pw[IDX] = pk;                                       \
        }

// Stage for tile T consuming adj regs A0/A1 (issued 2 stages ago),
// then reloading them with tile TP = min(T+2, tE):
//  order: issue bb(T) -> f2 LDS -> scores(A0,A1) -> reload A0,A1 -> MFMA(bb)
//  waits: scores' adj already drained by prior stage's bb wait (in-order);
//  MFMA's bb wait is a counted vmcnt (adj reload still in flight).
#define STAGE(T, A0, A1)                                                      \
    {                                                                         \
        const int tp = ((T) + 2 <= tE) ? (T) + 2 : tE;                        \
        u32x4 bb[8];                                                          \
        _Pragma("unroll")                                                     \
        for (int nt = 0; nt < 8; ++nt) bb[nt] = hb[((T) * 8 + nt) * 64];      \
        float4_ g0 = *(const float4_*)(f2s + (T) * 32 + quad * 8);            \
        float4_ g1 = *(const float4_*)(f2s + (T) * 32 + quad * 8 + 4);        \
        u32x4 pw;                                                             \
        float d = 0.f;                                                        \
        SC(g0[0], g0[1], A0[0], A0[1], 0)                                     \
        SC(g0[2], g0[3], A0[2], A0[3], 1)                                     \
        SC(g1[0], g1[1], A1[0], A1[1], 2)                                     \
        SC(g1[2], g1[3], A1[2], A1[3], 3)                                     \
        denacc += d;                                                          \
        const short8 af = __builtin_bit_cast(short8, pw);                     \
        A0 = ntload4(aprow + tp * 32);                                        \
        A1 = ntload4(aprow + tp * 32 + 4);                                    \
        _Pragma("unroll")                                                     \
        for (int nt = 0; nt < 8; ++nt)                                        \
            acc[nt] = __builtin_amdgcn_mfma_f32_16x16x32_bf16(                \
                af, __builtin_bit_cast(short8, bb[nt]), acc[nt], 0, 0, 0);    \
    }

    for (int o = 0; o < 16; ++o) {
        STAGE(t0 + 2 * o,     aA0, aA1)
        STAGE(t0 + 2 * o + 1, aB0, aB1)
    }
#undef STAGE
#undef SC

    // ---- denom: reduce over the 4 quads; one slot per (wh, row) ----
    denacc += __shfl_xor(denacc, 16, 64);
    denacc += __shfl_xor(denacc, 32, 64);
    if (quad == 0) dens2[wh * 32 + wr * 16 + lc] = denacc;
    __syncthreads();   // all loop reads of f2s done; Tsum alias safe

    // ---- merge token-half partials: wh0 writes, wh1 adds ----
    if (wh == 0) {
#pragma unroll
        for (int nt = 0; nt < 8; ++nt)
#pragma unroll
            for (int mm = 0; mm < 4; ++mm)
                Tsum[(wr * 16 + quad * 4 + mm) * WT_ + nt * 16 + lc] = acc[nt][mm];
    }
    __syncthreads();
    if (wh == 1) {
#pragma unroll
        for (int nt = 0; nt < 8; ++nt)
#pragma unroll
            for (int mm = 0; mm < 4; ++mm)
                Tsum[(wr * 16 + quad * 4 + mm) * WT_ + nt * 16 + lc] += acc[nt][mm];
    }
    __syncthreads();

    // ---- epilogue: out = elu( (T @ W_fp32) / den ), 32 rows ----
    {
        const int r  = tid >> 3;
        const int n0 = (tid & 7) * 8;
        const float den  = dens2[r] + dens2[32 + r];
        const float rden = (den > 0.f) ? (1.f / den) : 0.f;
        float u[8];
#pragma unroll
        for (int nn = 0; nn < 8; ++nn) u[nn] = 0.f;
#pragma unroll 4
        for (int k = 0; k < FIN_; ++k) {
            const float tv = Tsum[r * WT_ + k];
            float4_ wv0 = *(const float4_*)(W + k * F_ + n0);
            float4_ wv1 = *(const float4_*)(W + k * F_ + n0 + 4);
            u[0] += tv * wv0[0]; u[1] += tv * wv0[1];
            u[2] += tv * wv0[2]; u[3] += tv * wv0[3];
            u[4] += tv * wv1[0]; u[5] += tv * wv1[1];
            u[6] += tv * wv1[2]; u[7] += tv * wv1[3];
        }
        float4_ o0, o1;
#pragma unroll
        for (int nn = 0; nn < 8; ++nn) {
            float hp = u[nn] * rden;
            float o  = hp > 0.f ? hp : expm1f(hp);
            if (nn < 4) o0[nn] = o; else o1[nn - 4] = o;
        }
        float* op = out + ((size_t)(b * M_ + i0 + r)) * F_ + n0;
        *(float4_*)op       = o0;
        *(float4_*)(op + 4) = o1;
    }
}

// ---------------------------------------------------------------------------
extern "C" void kernel_launch(void* const* d_in, const int* in_sizes, int n_in,
                              void* d_out, int out_size, void* d_ws, size_t ws_size,
                              hipStream_t stream)
{
    (void)out_size; (void)ws_size;
    const float* h  = (const float*)d_in[0];
    const int* adjp = (const int*)d_in[1];
    const float* Wp = (const float*)d_in[2];
    const float* ap = (const float*)d_in[3];
    for (int i = 0; i < n_in; ++i) {
        long s = in_sizes[i];
        if      (s == 4194304L)  h    = (const float*)d_in[i];
        else if (s == 67108864L) adjp = (const int*)d_in[i];
        else if (s == 8192L)     Wp   = (const float*)d_in[i];
        else if (s == 128L)      ap   = (const float*)d_in[i];
    }
    u16*   hbf   = (u16*)d_ws;                                  // 8 MB
    float* f1all = (float*)((char*)d_ws + (8u << 20));          // 128 KB
    float* f2all = f1all + 16 * M_;                             // 128 KB
    k_prep<<<1024, 256, 0, stream>>>(h, Wp, ap, hbf, f1all, f2all);
    k_main<<<1024, 256, 0, stream>>>(adjp, hbf, f1all, f2all, Wp, (float*)d_out);
}

// Round 7
// 435.589 us; speedup vs baseline: 1.0285x; 1.0215x over previous
//
#include <hip/hip_runtime.h>

// GraphAttentionLayer v9: B=16, M=2048, F_IN=128, F_OUT=64, ALPHA=0.2
// out = elu( softmax_j( mask(adj, leaky_relu(f1_i + f2_j)) ) @ (h@W) )
// Algebra: h' = ((P @ h) @ W)/den, f1 = h@(W@a1), f2 = h@(W@a2).
//
// v9 root-cause fix. v5-v8 all ~155-170 us despite different schedules:
// VGPR=52/72 proved the AMDGPU scheduler SANK the 8 hbf B-frag loads to
// right before each MFMA use -> 8 serialized ~600cy L2 round-trips per
// tile (~5k cy/tile = the measured 372k cy). Fix: pin the schedule with
// __builtin_amdgcn_sched_barrier(0) fences per stage:
//   {8 bb loads} SB(0) {scores: 2-stage-old adj} {adj reload} SB(0) {8 MFMA}
// Backend then emits ONE counted vmcnt(2) per tile (adj pair stays in
// flight; in-order ripple drains last stage's adj for free -> loop never
// drains vmcnt to 0). Verification tell: VGPR must rise to ~110-128.
// Everything else identical to v8 (nt adj loads, token-split x2 TLP,
// 1024x256, merge + fp32-W epilogue).

#define M_     2048
#define FIN_   128
#define F_     64
#define ALPHA_ 0.2f
#define HS_    132     // k_prep LDS h-tile stride (floats)
#define WT_    132     // Tsum row stride (floats)

typedef float  float4_ __attribute__((ext_vector_type(4)));
typedef short  short8  __attribute__((ext_vector_type(8)));
typedef int    int4_   __attribute__((ext_vector_type(4)));
typedef unsigned int u32x4 __attribute__((ext_vector_type(4)));
typedef unsigned short u16;
typedef unsigned int   u32;

// packed f32x2 -> bf16x2 (RNE)
static __device__ __forceinline__ u32 cvtpk(float lo, float hi) {
    u32 r;
    asm("v_cvt_pk_bf16_f32 %0, %1, %2" : "=v"(r) : "v"(lo), "v"(hi));
    return r;
}

// non-temporal 16B load (nt cache bit: don't retain in L2/L3)
static __device__ __forceinline__ int4_ ntload4(const int* p) {
    return __builtin_nontemporal_load((const int4_*)p);
}

// ---------------------------------------------------------------------------
// Phase 1: hbf fragment layout: ((b*64 + t)*8 + nt)*64 + l  (16B per entry)
//   lane l of a wave holds B[n = nt*16 + (l&15)][k = (l>>4)*8 .. +7]
//   (tokens packed pairwise: u32 = bf16(tok_even) | bf16(tok_odd)<<16)
// ---------------------------------------------------------------------------
__global__ __launch_bounds__(256, 4) void k_prep(
    const float* __restrict__ h, const float* __restrict__ W,
    const float* __restrict__ a, u16* __restrict__ hbf,
    float* __restrict__ f1all, float* __restrict__ f2all)
{
    __shared__ float a_s[2 * F_];
    __shared__ float wa1[FIN_], wa2[FIN_];
    __shared__ float hs[32 * HS_];

    const int tid = threadIdx.x;
    const u32 bid = blockIdx.x;
    const u32 lg  = (bid & 7) * 128 + (bid >> 3);   // XCD x produces batches 2x,2x+1
    const int b   = lg >> 6;
    const int t   = lg & 63;

    if (tid < 128) a_s[tid] = a[tid];

    // h tile -> regs (coalesced float4)
    const int tok = tid >> 3, f0 = (tid & 7) * 16;
    const float* hp = h + ((size_t)(b * M_ + t * 32 + tok)) * FIN_ + f0;
    float4_ x0 = *(const float4_*)hp;
    float4_ x1 = *(const float4_*)(hp + 4);
    float4_ x2 = *(const float4_*)(hp + 8);
    float4_ x3 = *(const float4_*)(hp + 12);
    __syncthreads();   // a_s ready

    if (tid < FIN_) {
        float s1 = 0.f, s2 = 0.f;
#pragma unroll 8
        for (int n = 0; n < F_; ++n) {
            float wv = W[tid * F_ + n];
            s1 += wv * a_s[n];
            s2 += wv * a_s[F_ + n];
        }
        wa1[tid] = s1;
        wa2[tid] = s2;
    }

    float* hr = hs + tok * HS_ + f0;
    *(float4_*)(hr)      = x0;
    *(float4_*)(hr + 4)  = x1;
    *(float4_*)(hr + 8)  = x2;
    *(float4_*)(hr + 12) = x3;
    __syncthreads();   // hs + wa ready

    // ---- fragment conversion: thread handles lane l for nt0, nt0+1 ----
    {
        const int l = tid & 63, lc = l & 15, q = l >> 4;
        const int nt0 = (tid >> 6) * 2;
        u32x4* ob = (u32x4*)hbf + ((size_t)(b * 64 + t)) * 8 * 64;
#pragma unroll
        for (int ni = 0; ni < 2; ++ni) {
            const int nt = nt0 + ni;
            const float* cp = hs + (q * 8) * HS_ + nt * 16 + lc;
            u32x4 wv;
            wv[0] = cvtpk(cp[0 * HS_], cp[1 * HS_]);
            wv[1] = cvtpk(cp[2 * HS_], cp[3 * HS_]);
            wv[2] = cvtpk(cp[4 * HS_], cp[5 * HS_]);
            wv[3] = cvtpk(cp[6 * HS_], cp[7 * HS_]);
            ob[nt * 64 + l] = wv;
        }
    }

    // ---- f1/f2 per token (same reduction order as v8) ----
    {
        const int r = tid >> 3, k0 = (tid & 7) * 16;
        const float* rp = hs + r * HS_ + k0;
        float s1 = 0.f, s2 = 0.f;
#pragma unroll
        for (int k = 0; k < 16; ++k) {
            s1 += rp[k] * wa1[k0 + k];
            s2 += rp[k] * wa2[k0 + k];
        }
        s1 += __shfl_xor(s1, 1, 64); s2 += __shfl_xor(s2, 1, 64);
        s1 += __shfl_xor(s1, 2, 64); s2 += __shfl_xor(s2, 2, 64);
        s1 += __shfl_xor(s1, 4, 64); s2 += __shfl_xor(s2, 4, 64);
        if ((tid & 7) == 0) {
            f1all[b * M_ + t * 32 + r] = s1;
            f2all[b * M_ + t * 32 + r] = s2;
        }
    }
}

// ---------------------------------------------------------------------------
// Phase 2: 1024 blocks x 256 thr (4 waves). Wave (wr, wh): rows wr*16..+15,
// token half wh (32 tiles). Zero barriers in loop; sched_barrier-pinned
// stages; partials merged in LDS afterwards.
// ---------------------------------------------------------------------------
__global__ __launch_bounds__(256, 4) void k_main(
    const int* __restrict__ adj, const u16* __restrict__ hbf,
    const float* __restrict__ f1all, const float* __restrict__ f2all,
    const float* __restrict__ W, float* __restrict__ out)
{
    __shared__ char  dyn[WT_ * 32 * 4];   // f2s (8 KB) then Tsum (16.9 KB)
    __shared__ float dens2[64];

    float* f2s  = (float*)dyn;
    float* Tsum = (float*)dyn;

    const int tid  = threadIdx.x;
    const int w    = tid >> 6;
    const int l    = tid & 63;
    const int lc   = l & 15;
    const int quad = l >> 4;
    const int wr   = w & 1;      // row group (16 rows)
    const int wh   = w >> 1;     // token half (32 tiles)

    const u32 bid = blockIdx.x;
    const u32 lg  = (bid & 7) * 128 + (bid >> 3);   // XCD x consumes batches 2x,2x+1
    const int b   = lg >> 6;
    const int i0  = (lg & 63) * 32;
    const int rowbase = i0 + wr * 16;

    // stage f2all[b] -> LDS (8 KB, broadcast-read in loop)
    {
        const int o = tid * 8;
        float4_ v0 = *(const float4_*)(f2all + b * M_ + o);
        float4_ v1 = *(const float4_*)(f2all + b * M_ + o + 4);
        *(float4_*)(f2s + o)     = v0;
        *(float4_*)(f2s + o + 4) = v1;
    }

    const float f1r = f1all[b * M_ + rowbase + lc];
    const int* aprow = adj + ((size_t)(b * M_ + rowbase + lc)) * M_ + quad * 8;
    const u32x4* hb  = (const u32x4*)hbf + ((size_t)b * 64) * 8 * 64 + l;

    const int t0 = wh * 32;            // wave's first tile
    const int tE = t0 + 31;            // wave's last tile (clamp target)

    // prologue: adj tiles t0, t0+1 (nt, ping-pong depth 2)
    int4_ aA0 = ntload4(aprow + t0 * 32);
    int4_ aA1 = ntload4(aprow + t0 * 32 + 4);
    int4_ aB0 = ntload4(aprow + (t0 + 1) * 32);
    int4_ aB1 = ntload4(aprow + (t0 + 1) * 32 + 4);

    __syncthreads();   // f2s ready

    float denacc = 0.f;
    float4_ acc[8];
#pragma unroll
    for (int nt = 0; nt < 8; ++nt) acc[nt] = (float4_){0.f, 0.f, 0.f, 0.f};

#define SC(GE, GO, AE, AO, IDX)                                 \
        {                                                       \
            float xe = f1r + (GE); xe = fmaxf(xe, ALPHA_ * xe); \
            float xo = f1r + (GO); xo = fmaxf(xo, ALPHA_ * xo); \
            float ee = ((AE) > 0) ? __expf(xe) : 0.f;           \
            float eo = ((AO) > 0) ? __expf(xo) : 0.f;           \
            u32 pk = cvtpk(ee, eo);                             \
            d += __uint_as_float(pk << 16);                     \
            d += __uint_as_float(pk & 0xFFFF0000u);             \
            pw[IDX] = pk;                                       \
        }

// Stage for tile T consuming adj regs A0/A1 (issued 2 stages ago), then
// reloading them with tile min(T+2, tE). sched_barrier(0) fences forbid
// the scheduler from sinking the bb loads to their MFMA uses (the v5-v8
// failure: VGPR 52/72 proved loads were sunk -> 8 serial misses/tile).
// Backend emits one counted vmcnt(2) before the MFMAs; the adj pair
// issued here stays in flight across the next stage.
#define STAGE(T, A0, A1)                                                      \
    {                                                                         \
        const int tp = ((T) + 2 <= tE) ? (T) + 2 : tE;                        \
        u32x4 bb[8];                                                          \
        _Pragma("unroll")                                                     \
        for (int nt = 0; nt < 8; ++nt) bb[nt] = hb[((T) * 8 + nt) * 64];      \
        __builtin_amdgcn_sched_barrier(0);                                    \
        float4_ g0 = *(const float4_*)(f2s + (T) * 32 + quad * 8);            \
        float4_ g1 = *(const float4_*)(f2s + (T) * 32 + quad * 8 + 4);        \
        u32x4 pw;                                                             \
        float d = 0.f;                                                        \
        SC(g0[0], g0[1], A0[0], A0[1], 0)                                     \
        SC(g0[2], g0[3], A0[2], A0[3], 1)                                     \
        SC(g1[0], g1[1], A1[0], A1[1], 2)                                     \
        SC(g1[2], g1[3], A1[2], A1[3], 3)                                     \
        denacc += d;                                                          \
        const short8 af = __builtin_bit_cast(short8, pw);                     \
        A0 = ntload4(aprow + tp * 32);                                        \
        A1 = ntload4(aprow + tp * 32 + 4);                                    \
        __builtin_amdgcn_sched_barrier(0);                                    \
        _Pragma("unroll")                                                     \
        for (int nt = 0; nt < 8; ++nt)                                        \
            acc[nt] = __builtin_amdgcn_mfma_f32_16x16x32_bf16(                \
                af, __builtin_bit_cast(short8, bb[nt]), acc[nt], 0, 0, 0);    \
    }

    for (int o = 0; o < 16; ++o) {
        STAGE(t0 + 2 * o,     aA0, aA1)
        STAGE(t0 + 2 * o + 1, aB0, aB1)
    }
#undef STAGE
#undef SC

    // ---- denom: reduce over the 4 quads; one slot per (wh, row) ----
    denacc += __shfl_xor(denacc, 16, 64);
    denacc += __shfl_xor(denacc, 32, 64);
    if (quad == 0) dens2[wh * 32 + wr * 16 + lc] = denacc;
    __syncthreads();   // all loop reads of f2s done; Tsum alias safe

    // ---- merge token-half partials: wh0 writes, wh1 adds ----
    if (wh == 0) {
#pragma unroll
        for (int nt = 0; nt < 8; ++nt)
#pragma unroll
            for (int mm = 0; mm < 4; ++mm)
                Tsum[(wr * 16 + quad * 4 + mm) * WT_ + nt * 16 + lc] = acc[nt][mm];
    }
    __syncthreads();
    if (wh == 1) {
#pragma unroll
        for (int nt = 0; nt < 8; ++nt)
#pragma unroll
            for (int mm = 0; mm < 4; ++mm)
                Tsum[(wr * 16 + quad * 4 + mm) * WT_ + nt * 16 + lc] += acc[nt][mm];
    }
    __syncthreads();

    // ---- epilogue: out = elu( (T @ W_fp32) / den ), 32 rows ----
    {
        const int r  = tid >> 3;
        const int n0 = (tid & 7) * 8;
        const float den  = dens2[r] + dens2[32 + r];
        const float rden = (den > 0.f) ? (1.f / den) : 0.f;
        float u[8];
#pragma unroll
        for (int nn = 0; nn < 8; ++nn) u[nn] = 0.f;
#pragma unroll 4
        for (int k = 0; k < FIN_; ++k) {
            const float tv = Tsum[r * WT_ + k];
            float4_ wv0 = *(const float4_*)(W + k * F_ + n0);
            float4_ wv1 = *(const float4_*)(W + k * F_ + n0 + 4);
            u[0] += tv * wv0[0]; u[1] += tv * wv0[1];
            u[2] += tv * wv0[2]; u[3] += tv * wv0[3];
            u[4] += tv * wv1[0]; u[5] += tv * wv1[1];
            u[6] += tv * wv1[2]; u[7] += tv * wv1[3];
        }
        float4_ o0, o1;
#pragma unroll
        for (int nn = 0; nn < 8; ++nn) {
            float hp = u[nn] * rden;
            float o  = hp > 0.f ? hp : expm1f(hp);
            if (nn < 4) o0[nn] = o; else o1[nn - 4] = o;
        }
        float* op = out + ((size_t)(b * M_ + i0 + r)) * F_ + n0;
        *(float4_*)op       = o0;
        *(float4_*)(op + 4) = o1;
    }
}

// ---------------------------------------------------------------------------
extern "C" void kernel_launch(void* const* d_in, const int* in_sizes, int n_in,
                              void* d_out, int out_size, void* d_ws, size_t ws_size,
                              hipStream_t stream)
{
    (void)out_size; (void)ws_size;
    const float* h  = (const float*)d_in[0];
    const int* adjp = (const int*)d_in[1];
    const float* Wp = (const float*)d_in[2];
    const float* ap = (const float*)d_in[3];
    for (int i = 0; i < n_in; ++i) {
        long s = in_sizes[i];
        if      (s == 4194304L)  h    = (const float*)d_in[i];
        else if (s == 67108864L) adjp = (const int*)d_in[i];
        else if (s == 8192L)     Wp   = (const float*)d_in[i];
        else if (s == 128L)      ap   = (const float*)d_in[i];
    }
    u16*   hbf   = (u16*)d_ws;                                  // 8 MB
    float* f1all = (float*)((char*)d_ws + (8u << 20));          // 128 KB
    float* f2all = f1all + 16 * M_;                             // 128 KB
    k_prep<<<1024, 256, 0, stream>>>(h, Wp, ap, hbf, f1all, f2all);
    k_main<<<1024, 256, 0, stream>>>(adjp, hbf, f1all, f2all, Wp, (float*)d_out);
}